// Round 1
// baseline (233.148 us; speedup 1.0000x reference)
//
#include <hip/hip_runtime.h>
#include <math.h>

#define NB 65
#define HOPS 256
#define RPB 16          // rows per block
#define THREADS 256
#define RSTRIDE 644     // 512 noise_pad + 128 taps + 4 pad (breaks bank aliasing across rows)

// Per row (65536 total):
//   ir[n] = (1/128)*(A0 + 2*sum_{k=1..63} A_k cos(2pi k n/128) + A64*cos(pi n)), even symmetric.
//   tap[i] = 0.5*(1+cos(2pi i/128)) * ir[i],  i in [0,128); delay(i) = i<64 ? i : i+128.
//   out[t] = sum_i tap[i] * noise[t - delay(i)]  (causal, noise zero-padded), noise = 2u-1.
__global__ __launch_bounds__(THREADS) void noisefilter_kernel(
    const float* __restrict__ fb,   // [65536][65]
    const float* __restrict__ nz,   // [65536][256]
    float* __restrict__ out)        // [65536][256]
{
    __shared__ float lds[RPB * RSTRIDE];
    const int tid = threadIdx.x;
    const int r   = tid >> 4;        // row within block
    const int l16 = tid & 15;        // lane within row group
    const int t0  = l16 << 4;        // first output index of this thread
    const size_t row0 = (size_t)blockIdx.x * RPB;
    float* rowbuf = &lds[r * RSTRIDE];   // [0,512) noise_pad, [512,640) amp-then-taps

    // ---- stage amp (65 floats/row) into taps region ----
    const float* fbb = fb + row0 * NB;
    for (int i = tid; i < RPB * NB; i += THREADS) {
        int rr = i / NB;
        int k  = i - rr * NB;
        lds[rr * RSTRIDE + 512 + k] = fbb[i];
    }
    __syncthreads();

    // ---- Phase A: Goertzel, 5 chains per thread: n_j = l16 + 16j (valid if <= 64) ----
    float cj[5], s1[5], s2[5];
#pragma unroll
    for (int j = 0; j < 5; ++j) {
        cj[j] = __cosf((float)(l16 + 16 * j) * 0.0490873852123405f /* pi/64 */);
        s1[j] = 0.0f; s2[j] = 0.0f;
    }
    const float* amp = rowbuf + 512;
    {   // k = 64 (weight 1)
        float a = amp[64];
#pragma unroll
        for (int j = 0; j < 5; ++j) {
            float t = a - s2[j];
            float sn = fmaf(cj[j] + cj[j], s1[j], t);
            s2[j] = s1[j]; s1[j] = sn;
        }
    }
#pragma unroll
    for (int kb = 48; kb >= 0; kb -= 16) {   // k = kb+15 .. kb, weight 2 except k==0
        float ab[16];
#pragma unroll
        for (int x = 0; x < 4; ++x) {
            float4 v = *(const float4*)(amp + kb + 4 * x);
            ab[4*x] = v.x; ab[4*x+1] = v.y; ab[4*x+2] = v.z; ab[4*x+3] = v.w;
        }
#pragma unroll
        for (int kk = 15; kk >= 0; --kk) {
            float a  = ab[kk];
            float a2 = (kb + kk == 0) ? a : a + a;
#pragma unroll
            for (int j = 0; j < 5; ++j) {
                float t = a2 - s2[j];
                float sn = fmaf(cj[j] + cj[j], s1[j], t);
                s2[j] = s1[j]; s1[j] = sn;
            }
        }
    }
    __syncthreads();   // amp reads done; taps region may be overwritten now

    // ---- write taps (symmetric pair) ----
#pragma unroll
    for (int j = 0; j < 5; ++j) {
        int nj = l16 + 16 * j;
        if (nj <= 64) {
            float G = s1[j] - cj[j] * s2[j];                 // 128*ir[nj]
            float T = G * (1.0f + cj[j]) * (1.0f / 256.0f); // 0.5*(1+c)/128
            rowbuf[512 + nj] = T;
            if (nj >= 1 && nj <= 63) rowbuf[512 + 128 - nj] = T;
        }
    }

    // ---- zero pad region [0,256) of own row ----
#pragma unroll
    for (int x = 0; x < 4; ++x)
        *(float4*)(rowbuf + t0 + 4 * x) = make_float4(0.f, 0.f, 0.f, 0.f);

    // ---- stage noise (2u-1) into [256,512) ----
    const float4* nz4 = (const float4*)(nz + row0 * HOPS);
#pragma unroll
    for (int p = 0; p < 4; ++p) {
        int idx = tid + p * THREADS;
        float4 v = nz4[idx];
        int rr = idx >> 6;             // 64 float4 per row
        int o  = (idx & 63) << 2;
        *(float4*)(&lds[rr * RSTRIDE + 256 + o]) =
            make_float4(fmaf(2.f, v.x, -1.f), fmaf(2.f, v.y, -1.f),
                        fmaf(2.f, v.z, -1.f), fmaf(2.f, v.w, -1.f));
    }
    __syncthreads();

    // ---- Phase C: register-blocked FIR. 16 outputs/thread, 8 chunks of 16 taps ----
    float f[16];
#pragma unroll
    for (int d = 0; d < 16; ++d) f[d] = 0.f;
#pragma unroll
    for (int ch = 0; ch < 8; ++ch) {
        const int off  = (ch < 4) ? 256 : 128;       // delay = i (i<64) or i+128 (i>=64)
        const int base = off + t0 - 16 * ch - 16;    // 64B-aligned, always in [0,480]
        float w[32];
#pragma unroll
        for (int x = 0; x < 8; ++x) {
            float4 v = *(const float4*)(rowbuf + base + 4 * x);
            w[4*x] = v.x; w[4*x+1] = v.y; w[4*x+2] = v.z; w[4*x+3] = v.w;
        }
        float tp[16];
#pragma unroll
        for (int x = 0; x < 4; ++x) {
            float4 v = *(const float4*)(rowbuf + 512 + 16 * ch + 4 * x);
            tp[4*x] = v.x; tp[4*x+1] = v.y; tp[4*x+2] = v.z; tp[4*x+3] = v.w;
        }
#pragma unroll
        for (int kk = 0; kk < 16; ++kk) {
#pragma unroll
            for (int d = 0; d < 16; ++d)
                f[d] = fmaf(tp[kk], w[16 + d - kk], f[d]);   // index in [1,31]
        }
    }

    // ---- store ----
    float* op = out + (row0 + r) * HOPS + t0;
#pragma unroll
    for (int x = 0; x < 4; ++x)
        *(float4*)(op + 4 * x) = make_float4(f[4*x], f[4*x+1], f[4*x+2], f[4*x+3]);
}

extern "C" void kernel_launch(void* const* d_in, const int* in_sizes, int n_in,
                              void* d_out, int out_size, void* d_ws, size_t ws_size,
                              hipStream_t stream) {
    const float* fb = (const float*)d_in[0];
    const float* nz = (const float*)d_in[1];
    float* o = (float*)d_out;
    const int rows = 16 * 4096;              // 65536
    noisefilter_kernel<<<dim3(rows / RPB), dim3(THREADS), 0, stream>>>(fb, nz, o);
}

// Round 2
// 175.324 us; speedup vs baseline: 1.3298x; 1.3298x over previous
//
#include <hip/hip_runtime.h>
#include <math.h>

#define NB 65
#define HOPS 256
#define RPB 16          // rows per block
#define THREADS 256
#define TAPS_OFF 576    // phys size of swizzled 512-float noise_pad region (512 + 16*4 pad)
#define RSTRIDE 708     // 576 noise_pad(phys) + 128 taps + 4 pad (708%32==4 rotates rows)

// Swizzle for the noise_pad region: +4 floats of pad every 32 floats.
// Makes 64B-lane-stride ds_read_b128 hit all 8 bank-quads per 8-lane group.
#define PHYS(i) ((i) + (((i) >> 5) << 2))

// Per row (65536 total):
//   ir[n] = (1/128)*(A0 + 2*sum_{k=1..63} A_k cos(2pi k n/128) + A64*cos(pi n)), even symmetric.
//   tap[i] = 0.5*(1+cos(2pi i/128)) * ir[i],  i in [0,128); delay(i) = i<64 ? i : i+128.
//   out[t] = sum_i tap[i] * noise[t - delay(i)]  (causal, noise zero-padded), noise = 2u-1.
__global__ __launch_bounds__(THREADS) void noisefilter_kernel(
    const float* __restrict__ fb,   // [65536][65]
    const float* __restrict__ nz,   // [65536][256]
    float* __restrict__ out)        // [65536][256]
{
    __shared__ float lds[RPB * RSTRIDE];
    const int tid = threadIdx.x;
    const int r   = tid >> 4;        // row within block
    const int l16 = tid & 15;        // lane within row group
    const int t0  = l16 << 4;        // first output index of this thread
    const size_t row0 = (size_t)blockIdx.x * RPB;
    float* rowbuf = &lds[r * RSTRIDE];   // [0,576) swizzled noise_pad, [576,704) amp-then-taps

    // ---- stage amp (65 floats/row) into taps region ----
    const float* fbb = fb + row0 * NB;
    for (int i = tid; i < RPB * NB; i += THREADS) {
        int rr = i / NB;
        int k  = i - rr * NB;
        lds[rr * RSTRIDE + TAPS_OFF + k] = fbb[i];
    }
    __syncthreads();

    // ---- Phase A: Goertzel, 5 chains per thread: n_j = l16 + 16j (valid if <= 64) ----
    float cj[5], s1[5], s2[5];
#pragma unroll
    for (int j = 0; j < 5; ++j) {
        cj[j] = __cosf((float)(l16 + 16 * j) * 0.0490873852123405f /* pi/64 */);
        s1[j] = 0.0f; s2[j] = 0.0f;
    }
    const float* amp = rowbuf + TAPS_OFF;
    {   // k = 64 (weight 1)
        float a = amp[64];
#pragma unroll
        for (int j = 0; j < 5; ++j) {
            float t = a - s2[j];
            float sn = fmaf(cj[j] + cj[j], s1[j], t);
            s2[j] = s1[j]; s1[j] = sn;
        }
    }
#pragma unroll
    for (int kb = 48; kb >= 0; kb -= 16) {   // k = kb+15 .. kb, weight 2 except k==0
        float ab[16];
#pragma unroll
        for (int x = 0; x < 4; ++x) {
            float4 v = *(const float4*)(amp + kb + 4 * x);
            ab[4*x] = v.x; ab[4*x+1] = v.y; ab[4*x+2] = v.z; ab[4*x+3] = v.w;
        }
#pragma unroll
        for (int kk = 15; kk >= 0; --kk) {
            float a  = ab[kk];
            float a2 = (kb + kk == 0) ? a : a + a;
#pragma unroll
            for (int j = 0; j < 5; ++j) {
                float t = a2 - s2[j];
                float sn = fmaf(cj[j] + cj[j], s1[j], t);
                s2[j] = s1[j]; s1[j] = sn;
            }
        }
    }
    __syncthreads();   // amp reads done; taps region may be overwritten now

    // ---- write taps (symmetric pair) ----
#pragma unroll
    for (int j = 0; j < 5; ++j) {
        int nj = l16 + 16 * j;
        if (nj <= 64) {
            float G = s1[j] - cj[j] * s2[j];                 // 128*ir[nj]
            float T = G * (1.0f + cj[j]) * (1.0f / 256.0f); // 0.5*(1+c)/128
            rowbuf[TAPS_OFF + nj] = T;
            if (nj >= 1 && nj <= 63) rowbuf[TAPS_OFF + 128 - nj] = T;
        }
    }

    // ---- zero pad region logical [0,256) of own row (swizzled) ----
#pragma unroll
    for (int x = 0; x < 4; ++x)
        *(float4*)(rowbuf + PHYS(t0 + 4 * x)) = make_float4(0.f, 0.f, 0.f, 0.f);

    // ---- stage noise (2u-1) into logical [256,512) (swizzled) ----
    const float4* nz4 = (const float4*)(nz + row0 * HOPS);
#pragma unroll
    for (int p = 0; p < 4; ++p) {
        int idx = tid + p * THREADS;
        float4 v = nz4[idx];
        int rr = idx >> 6;             // 64 float4 per row
        int o  = ((idx & 63) << 2) + 256;
        *(float4*)(&lds[rr * RSTRIDE + PHYS(o)]) =
            make_float4(fmaf(2.f, v.x, -1.f), fmaf(2.f, v.y, -1.f),
                        fmaf(2.f, v.z, -1.f), fmaf(2.f, v.w, -1.f));
    }
    __syncthreads();

    // ---- Phase C: register-blocked FIR. 16 outputs/thread, 8 chunks of 16 taps ----
    float f[16];
#pragma unroll
    for (int d = 0; d < 16; ++d) f[d] = 0.f;
#pragma unroll
    for (int ch = 0; ch < 8; ++ch) {
        const int off  = (ch < 4) ? 256 : 128;       // delay = i (i<64) or i+128 (i>=64)
        const int base = off + t0 - 16 * ch - 16;    // 16B-aligned logical, in [0,480]
        float w[32];
#pragma unroll
        for (int x = 0; x < 8; ++x) {
            int L = base + 4 * x;
            float4 v = *(const float4*)(rowbuf + PHYS(L));
            w[4*x] = v.x; w[4*x+1] = v.y; w[4*x+2] = v.z; w[4*x+3] = v.w;
        }
        float tp[16];
#pragma unroll
        for (int x = 0; x < 4; ++x) {
            float4 v = *(const float4*)(rowbuf + TAPS_OFF + 16 * ch + 4 * x);
            tp[4*x] = v.x; tp[4*x+1] = v.y; tp[4*x+2] = v.z; tp[4*x+3] = v.w;
        }
#pragma unroll
        for (int kk = 0; kk < 16; ++kk) {
#pragma unroll
            for (int d = 0; d < 16; ++d)
                f[d] = fmaf(tp[kk], w[16 + d - kk], f[d]);   // index in [1,31]
        }
    }

    // ---- store ----
    float* op = out + (row0 + r) * HOPS + t0;
#pragma unroll
    for (int x = 0; x < 4; ++x)
        *(float4*)(op + 4 * x) = make_float4(f[4*x], f[4*x+1], f[4*x+2], f[4*x+3]);
}

extern "C" void kernel_launch(void* const* d_in, const int* in_sizes, int n_in,
                              void* d_out, int out_size, void* d_ws, size_t ws_size,
                              hipStream_t stream) {
    const float* fb = (const float*)d_in[0];
    const float* nz = (const float*)d_in[1];
    float* o = (float*)d_out;
    const int rows = 16 * 4096;              // 65536
    noisefilter_kernel<<<dim3(rows / RPB), dim3(THREADS), 0, stream>>>(fb, nz, o);
}

// Round 4
// 153.272 us; speedup vs baseline: 1.5211x; 1.1439x over previous
//
#include <hip/hip_runtime.h>
#include <math.h>

#define NB 65
#define HOPS 256
#define RPB 8           // rows per block
#define THREADS 128     // 16 lanes per row
#define TAPS_OFF 360    // phys size of swizzled 320-float pad region (320 + 10*4 pad)
#define RSTRIDE 492     // 360 pad(phys) + 128 taps + 4 (492%32==12 rotates rows)

// Swizzle: +4 floats of pad every 32 floats (logical pad region [0,320)).
// Logical layout per row: [0,64) zeros, [64,320) noise (2u-1); taps at [TAPS_OFF,+128).
#define PHYS(i) ((i) + (((i) >> 5) << 2))

__device__ __forceinline__ void load16(float (&d)[16], const float* p) {
#pragma unroll
    for (int x = 0; x < 4; ++x) {
        float4 v = *(const float4*)(p + 4 * x);
        d[4*x] = v.x; d[4*x+1] = v.y; d[4*x+2] = v.z; d[4*x+3] = v.w;
    }
}
__device__ __forceinline__ void load16s(float (&d)[16], const float* rowbuf, int L) {
#pragma unroll
    for (int x = 0; x < 4; ++x) {
        float4 v = *(const float4*)(rowbuf + PHYS(L + 4 * x));
        d[4*x] = v.x; d[4*x+1] = v.y; d[4*x+2] = v.z; d[4*x+3] = v.w;
    }
}
// window w[j] = j<16 ? lo[j] : hi[j-16], j = 16+d-kk in [1,31]
__device__ __forceinline__ void fma16(float (&f)[16], const float (&tp)[16],
                                      const float (&lo)[16], const float (&hi)[16]) {
#pragma unroll
    for (int kk = 0; kk < 16; ++kk) {
        float t = tp[kk];
#pragma unroll
        for (int d = 0; d < 16; ++d) {
            int j = 16 + d - kk;
            f[d] = fmaf(t, (j < 16) ? lo[j] : hi[j - 16], f[d]);
        }
    }
}

__global__ __launch_bounds__(THREADS, 4) void noisefilter_kernel(
    const float* __restrict__ fb,   // [65536][65]
    const float* __restrict__ nz,   // [65536][256]
    float* __restrict__ out)        // [65536][256]
{
    __shared__ float lds[RPB * RSTRIDE];
    const int tid = threadIdx.x;
    const int r   = tid >> 4;        // row within block (0..7)
    const int l16 = tid & 15;        // lane within row group
    const int t0  = l16 << 4;        // first output index of this thread
    const size_t row0 = (size_t)blockIdx.x * RPB;
    float* rowbuf = &lds[r * RSTRIDE];

    // ---- stage amp (65 floats/row) ----
    const float* fbb = fb + row0 * NB;
    for (int i = tid; i < RPB * NB; i += THREADS) {
        int rr = i / NB;
        int k  = i - rr * NB;
        lds[rr * RSTRIDE + TAPS_OFF + k] = fbb[i];
    }

    // ---- prefetch noise into registers (consumed after Goertzel) ----
    const float4* nz4 = (const float4*)(nz + row0 * HOPS);
    float4 nv[4];
#pragma unroll
    for (int p = 0; p < 4; ++p) nv[p] = nz4[tid + p * THREADS];

    __syncthreads();

    // ---- Phase A: even/odd-split Goertzel; lane gets (nA,64-nA),(nB,64-nB), n=32 shared.
    const float alphaA = (float)l16 * 0.04908738521234052f;          // pi/64 * nA
    const float alphaB = alphaA + 0.7853981633974483f;               // + pi/4
    const float cA = __cosf(alphaA), cB = __cosf(alphaB);
    const float c2A = fmaf(2.0f * cA, cA, -1.0f);                    // cos(2a)
    const float c2B = fmaf(2.0f * cB, cB, -1.0f);
    const float k2A = c2A + c2A, k2B = c2B + c2B;

    float eA1=0.f,eA2=0.f,oA1=0.f,oA2=0.f;
    float eB1=0.f,eB2=0.f,oB1=0.f,oB2=0.f;
    float s32 = 0.f, a0r = 0.f, a64r;

    const float* amp = rowbuf + TAPS_OFF;
    {   // k = 64 (even chain m=32; n=32 sign +)
        float a = amp[64];
        a64r = a;
        { float t = a - eA2; float s = fmaf(k2A, eA1, t); eA2 = eA1; eA1 = s; }
        { float t = a - eB2; float s = fmaf(k2B, eB1, t); eB2 = eB1; eB1 = s; }
        s32 += a;
    }
#pragma unroll
    for (int kb = 48; kb >= 0; kb -= 16) {
        float ab[16];
        load16(ab, amp + kb);
#pragma unroll
        for (int kk = 15; kk >= 0; --kk) {
            float a = ab[kk];
            if (kk & 1) {   // odd k
                { float t = a - oA2; float s = fmaf(k2A, oA1, t); oA2 = oA1; oA1 = s; }
                { float t = a - oB2; float s = fmaf(k2B, oB1, t); oB2 = oB1; oB1 = s; }
            } else {        // even k
                { float t = a - eA2; float s = fmaf(k2A, eA1, t); eA2 = eA1; eA1 = s; }
                { float t = a - eB2; float s = fmaf(k2B, eB1, t); eB2 = eB1; eB1 = s; }
                if ((kk >> 1) & 1) s32 -= a; else s32 += a;
            }
        }
        if (kb == 0) a0r = ab[0];
    }

    const float EA = fmaf(-c2A, eA2, eA1);
    const float OA = cA * (oA1 - oA2);
    const float EB = fmaf(-c2B, eB2, eB1);
    const float OB = cB * (oB1 - oB2);
    const float pm = (l16 & 1) ? -1.f : 1.f;      // (-1)^n
    const float corr = fmaf(pm, a64r, a0r);
    const float inv = 1.0f / 256.0f;
    float* tps = rowbuf + TAPS_OFF;

    {   // pair A: n = l16, mirror 64-l16
        float GA  = fmaf(2.f, EA + OA, -corr);
        float GAm = fmaf(2.f, EA - OA, -corr);
        float TA  = GA  * (1.0f + cA) * inv;
        float TAm = GAm * (1.0f - cA) * inv;
        tps[l16] = TA;
        tps[64 - l16] = TAm;
        if (l16 >= 1) { tps[128 - l16] = TA; tps[64 + l16] = TAm; }
    }
    {   // pair B: n = 16+l16, mirror 48-l16
        float GB  = fmaf(2.f, EB + OB, -corr);
        float GBm = fmaf(2.f, EB - OB, -corr);
        float TB  = GB  * (1.0f + cB) * inv;
        float TBm = GBm * (1.0f - cB) * inv;
        tps[16 + l16] = TB;  tps[112 - l16] = TB;
        tps[48 - l16] = TBm; tps[80 + l16]  = TBm;
    }
    {   // n = 32
        float G32 = fmaf(2.f, s32, -(a0r + a64r));
        float T32 = G32 * inv;
        tps[32] = T32;
        tps[96] = T32;
    }

    // ---- zero logical [0,64) of own row (one float4 per lane) ----
    *(float4*)(rowbuf + PHYS(4 * l16)) = make_float4(0.f, 0.f, 0.f, 0.f);

    // ---- store noise (2u-1) into logical [64,320) ----
#pragma unroll
    for (int p = 0; p < 4; ++p) {
        int idx = tid + p * THREADS;
        float4 v = nv[p];
        int rr = idx >> 6;
        int o  = ((idx & 63) << 2) + 64;
        *(float4*)(&lds[rr * RSTRIDE + PHYS(o)]) =
            make_float4(fmaf(2.f, v.x, -1.f), fmaf(2.f, v.y, -1.f),
                        fmaf(2.f, v.z, -1.f), fmaf(2.f, v.w, -1.f));
    }
    __syncthreads();

    // ---- Phase C1: taps 0..63 (delays 0..63), all 256 outputs, sliding window ----
    float f[16];
#pragma unroll
    for (int d = 0; d < 16; ++d) f[d] = 0.f;
    float X[16], Y[16], Z[16], tp[16];
    {
        const int b0 = t0 + 48;
        load16s(X, rowbuf, b0);      load16s(Y, rowbuf, b0 + 16);
        load16(tp, tps + 0);   fma16(f, tp, X, Y);
        load16s(Z, rowbuf, b0 - 16);
        load16(tp, tps + 16);  fma16(f, tp, Z, X);
        load16s(Y, rowbuf, b0 - 32);
        load16(tp, tps + 32);  fma16(f, tp, Y, Z);
        load16s(X, rowbuf, b0 - 48);
        load16(tp, tps + 48);  fma16(f, tp, X, Y);
    }

    // ---- Phase C2: tail taps 64..127 (delays 192..255) -> only outputs t>=192.
    //      Dense assignment: lane l16 computes partials for t' = 192+4*l16+{0..3}.
    float g[4] = {0.f, 0.f, 0.f, 0.f};
#pragma unroll
    for (int c = 0; c < 4; ++c) {
        float W[20];
#pragma unroll
        for (int x = 0; x < 5; ++x) {
            float4 v = *(const float4*)(rowbuf + PHYS(48 + 4 * l16 - 16 * c + 4 * x));
            W[4*x] = v.x; W[4*x+1] = v.y; W[4*x+2] = v.z; W[4*x+3] = v.w;
        }
        float tp2[16];
        load16(tp2, tps + 64 + 16 * c);
#pragma unroll
        for (int kk = 0; kk < 16; ++kk) {
            float t = tp2[kk];
#pragma unroll
            for (int d = 0; d < 4; ++d)
                g[d] = fmaf(t, W[16 + d - kk], g[d]);   // index in [1,19]
        }
    }
    // exchange partials via row scratch (overwrites taps[64..128) — all reads done;
    // same-wave DS ops are in-order, no barrier needed)
    *(float4*)(tps + 64 + 4 * l16) = make_float4(g[0], g[1], g[2], g[3]);
    if (l16 >= 12) {
        const float* sc = tps + 64 + ((l16 - 12) << 4);
#pragma unroll
        for (int x = 0; x < 4; ++x) {
            float4 v = *(const float4*)(sc + 4 * x);
            f[4*x]   += v.x; f[4*x+1] += v.y;
            f[4*x+2] += v.z; f[4*x+3] += v.w;
        }
    }

    // ---- store ----
    float* op = out + (row0 + r) * HOPS + t0;
#pragma unroll
    for (int x = 0; x < 4; ++x)
        *(float4*)(op + 4 * x) = make_float4(f[4*x], f[4*x+1], f[4*x+2], f[4*x+3]);
}

extern "C" void kernel_launch(void* const* d_in, const int* in_sizes, int n_in,
                              void* d_out, int out_size, void* d_ws, size_t ws_size,
                              hipStream_t stream) {
    const float* fb = (const float*)d_in[0];
    const float* nz = (const float*)d_in[1];
    float* o = (float*)d_out;
    const int rows = 16 * 4096;              // 65536
    noisefilter_kernel<<<dim3(rows / RPB), dim3(THREADS), 0, stream>>>(fb, nz, o);
}